// Round 10
// baseline (1241.529 us; speedup 1.0000x reference)
//
#include <hip/hip_runtime.h>
#include <hip/hip_fp16.h>
#include <stdint.h>

#define B_  32
#define S_  32
#define V_  100
#define HD_ 32
#define HID_ 64
#define ND_ 10
#define NROW (B_*V_)
#define NTILE 7
#define NBLK (B_*NTILE)   // 224 blocks
#define NFRAG 58

// ---- workspace float offsets ----
#define WO_EP    14848                          // 58 frags * 64 * 4 floats before this
#define WO_HA    24848
#define WO_HB    127248
#define WO_ACC   229648
#define WO_PREVL 232848
#define WO_PREVT 236048
#define WO_LTLOG 239248

typedef __attribute__((ext_vector_type(8))) _Float16 f16x8;
typedef __attribute__((ext_vector_type(4))) float f32x4;

#define LGKM_FENCE asm volatile("s_waitcnt lgkmcnt(0)" ::: "memory")

// ---------------- threefry2x32 (JAX-compatible, verified) ----------------
__host__ __device__ inline void tf2x32(uint32_t k0, uint32_t k1,
                                       uint32_t& x0, uint32_t& x1) {
  uint32_t ks0 = k0, ks1 = k1, ks2 = k0 ^ k1 ^ 0x1BD11BDAu;
#define TFR(r) { x0 += x1; x1 = (x1 << (r)) | (x1 >> (32 - (r))); x1 ^= x0; }
  x0 += ks0; x1 += ks1;
  TFR(13) TFR(15) TFR(26) TFR(6)
  x0 += ks1; x1 += ks2 + 1u;
  TFR(17) TFR(29) TFR(16) TFR(24)
  x0 += ks2; x1 += ks0 + 2u;
  TFR(13) TFR(15) TFR(26) TFR(6)
  x0 += ks0; x1 += ks1 + 3u;
  TFR(17) TFR(29) TFR(16) TFR(24)
  x0 += ks1; x1 += ks2 + 4u;
  TFR(13) TFR(15) TFR(26) TFR(6)
  x0 += ks2; x1 += ks0 + 5u;
#undef TFR
}

// ---------------- erfinv (XLA / Giles f32 polynomial) ----------------
__device__ __forceinline__ float erfinv_f(float x) {
  float w = -log1pf(-x * x);
  float p;
  if (w < 5.0f) {
    w -= 2.5f;
    p = 2.81022636e-08f;
    p = fmaf(p, w, 3.43273939e-07f);
    p = fmaf(p, w, -3.5233877e-06f);
    p = fmaf(p, w, -4.39150654e-06f);
    p = fmaf(p, w, 0.00021858087f);
    p = fmaf(p, w, -0.00125372503f);
    p = fmaf(p, w, -0.00417768164f);
    p = fmaf(p, w, 0.246640727f);
    p = fmaf(p, w, 1.50140941f);
  } else {
    w = sqrtf(w) - 3.0f;
    p = -0.000200214257f;
    p = fmaf(p, w, 0.000100950558f);
    p = fmaf(p, w, 0.00134934322f);
    p = fmaf(p, w, -0.00367342844f);
    p = fmaf(p, w, 0.00573950773f);
    p = fmaf(p, w, -0.0076224613f);
    p = fmaf(p, w, 0.00943887047f);
    p = fmaf(p, w, 1.00167406f);
    p = fmaf(p, w, 2.83297682f);
  }
  return p * x;
}

// ---------------- fast device math ----------------
__device__ __forceinline__ float tanh_e(float x) {
  float e = __builtin_amdgcn_exp2f(x * 2.885390082f);
  return 1.0f - 2.0f * __builtin_amdgcn_rcpf(e + 1.0f);
}
__device__ __forceinline__ float softplus_fast(float x) {
  return fmaxf(x, 0.0f) + __logf(1.0f + __expf(-fabsf(x)));
}
__device__ __forceinline__ unsigned short f16b(float x) {
  __half h = __float2half(x);
  return *reinterpret_cast<unsigned short*>(&h);
}
__device__ __forceinline__ uint32_t pk2(float a, float b) {
  return (uint32_t)f16b(a) | ((uint32_t)f16b(b) << 16);
}
__device__ __forceinline__ f32x4 MF(f16x8 a, f16x8 b, f32x4 c) {
  return __builtin_amdgcn_mfma_f32_16x16x32_f16(a, b, c, 0, 0, 0);
}

struct SubK { uint32_t k[ND_][2]; };

// half of noise8: t fixed; values for rows row0+4g+reg, dim li+16t (bit-identical halves)
__device__ __forceinline__ void noise4(int row0, int lane, int t, uint32_t k0, uint32_t k1,
                                       float* n) {
  int g = lane >> 4, li = lane & 15;
#pragma unroll
  for (int reg = 0; reg < 4; ++reg) {
    int row = row0 + 4 * g + reg;
    uint32_t x0 = 0u, x1 = (uint32_t)(row * HD_ + li + 16 * t);
    tf2x32(k0, k1, x0, x1);
    uint32_t bits = x0 ^ x1;
    float fr = __uint_as_float(0x3f800000u | (bits >> 9)) - 1.0f;
    const float LOW = -0.99999994f;
    float u = fmaxf(LOW, fr * 2.0f + LOW);
    n[reg] = 1.4142135f * erfinv_f(u);
  }
}

// ---------------- prep: 58 f16 MFMA B-fragments + edge_prob (round-8/9 verified) ----------------
__global__ void prep_k(const float* __restrict__ fW1, const float* __restrict__ gW1,
                       const float* __restrict__ fW2, const float* __restrict__ gW2,
                       const float* __restrict__ fW3, const float* __restrict__ gW3,
                       const float* __restrict__ eW1, const float* __restrict__ eW2,
                       const float* __restrict__ mW1, const float* __restrict__ mW2,
                       const float* __restrict__ jW1, const float* __restrict__ jW2,
                       const float* __restrict__ logits, float* __restrict__ ws) {
  int tid = blockIdx.x * 256 + threadIdx.x;
  if (tid < NFRAG * 64) {
    int fid = tid >> 6, lane = tid & 63;
    int g = lane >> 4, li = lane & 15;
    const float* src; int k0 = 0, n0 = 0, ncol = HID_; bool hperm = false, col0 = false;
    if (fid < 4)       { src = fW1; n0 = 16 * fid;       hperm = true; }
    else if (fid < 8)  { src = gW1; n0 = 16 * (fid - 4); hperm = true; }
    else if (fid < 16) { int q = fid - 8;  src = fW2; n0 = 16 * (q >> 1); k0 = 32 * (q & 1); }
    else if (fid < 24) { int q = fid - 16; src = gW2; n0 = 16 * (q >> 1); k0 = 32 * (q & 1); }
    else if (fid < 28) { int q = fid - 24; src = fW3; n0 = 16 * (q >> 1); k0 = 32 * (q & 1); ncol = HD_; }
    else if (fid < 32) { int q = fid - 28; src = gW3; n0 = 16 * (q >> 1); k0 = 32 * (q & 1); ncol = HD_; }
    else if (fid < 36) { src = eW1; n0 = 16 * (fid - 32); hperm = true; }
    else if (fid < 38) { src = eW2; k0 = 32 * (fid - 36); col0 = true; }
    else if (fid < 46) { int q = fid - 38; src = mW1; k0 = 32 * (q >> 2); n0 = 16 * (q & 3); hperm = true; }
    else if (fid < 50) { int q = fid - 46; src = mW2; k0 = 32 * (q >> 1); n0 = 16 * (q & 1); ncol = HD_; }
    else if (fid < 54) { src = jW1; n0 = 16 * (fid - 50); hperm = true; }
    else               { int q = fid - 54; src = jW2; k0 = 32 * (q >> 1); n0 = 16 * (q & 1); ncol = HD_; }
    unsigned short v[8];
#pragma unroll
    for (int j = 0; j < 8; ++j) {
      int sl = 8 * g + j;
      int k;
      if (hperm) k = k0 + ((sl >> 1) + 16 * (sl & 1));
      else { int s2 = k0 + sl; k = (s2 >> 2) + 16 * (s2 & 3); }
      float x;
      if (col0) x = (li == 0) ? src[k] : 0.0f;
      else      x = src[k * ncol + (n0 + li)];
      v[j] = f16b(x);
    }
    uint4 o;
    o.x = (uint32_t)v[0] | ((uint32_t)v[1] << 16);
    o.y = (uint32_t)v[2] | ((uint32_t)v[3] << 16);
    o.z = (uint32_t)v[4] | ((uint32_t)v[5] << 16);
    o.w = (uint32_t)v[6] | ((uint32_t)v[7] << 16);
    ((uint4*)ws)[fid * 64 + lane] = o;
  } else if (tid < NFRAG * 64 + V_ * V_) {
    int idx = tid - NFRAG * 64;
    float l0v = logits[idx], l1v = logits[V_ * V_ + idx];
    float mx = fmaxf(l0v, l1v);
    float e0 = expf(l0v - mx), e1 = expf(l1v - mx);
    ws[WO_EP + idx] = e1 / (e0 + e1);
  }
}

// used by init_k only
template<int K4, int O>
__device__ __forceinline__ float dotWxT(const float* __restrict__ W,
                                        const float* __restrict__ x,
                                        float a, int lane) {
#pragma unroll
  for (int kb = 0; kb < K4; ++kb) {
    float4 xv = *(const float4*)(x + kb * 4);
    a = fmaf(xv.x, W[(kb * 4 + 0) * O + lane], a);
    a = fmaf(xv.y, W[(kb * 4 + 1) * O + lane], a);
    a = fmaf(xv.z, W[(kb * 4 + 2) * O + lane], a);
    a = fmaf(xv.w, W[(kb * 4 + 3) * O + lane], a);
  }
  return a;
}

// ---------------- init: hA = broadcast(h0); l0; lt0; acc=0 ----------------
__launch_bounds__(256)
__global__ void init_k(const int* __restrict__ type_, const float* __restrict__ mask_,
                       const float* __restrict__ h0,
                       const float* __restrict__ eW1, const float* __restrict__ eb1,
                       const float* __restrict__ eW2, const float* __restrict__ eb2,
                       float* __restrict__ hA, float* __restrict__ acc,
                       float* __restrict__ ltlog, float* __restrict__ dout) {
  __shared__ float xls[4][64];
  const int w = threadIdx.x >> 6, lane = threadIdx.x & 63;
  const int row = blockIdx.x * 4 + w;
  const int b = row / V_, v = row - b * V_;
  if (lane < 32) {
    float x = h0[v * HD_ + lane];
    xls[w][lane] = x;
    hA[row * HD_ + lane] = x;
  }
  float a = dotWxT<8, 64>(eW1, xls[w], eb1[lane], lane);
  float t = tanhf(a) * eW2[lane];
#pragma unroll
  for (int o = 1; o < 64; o <<= 1) t += __shfl_xor(t, o, 64);
  float z = t + eb2[0];
  float l0 = fmaxf(z, 0.0f) + log1pf(expf(-fabsf(z)));
  if (lane == 0) {
    dout[1 + (b * S_ + 0) * V_ + v] = l0;
    acc[row] = 0.0f;
    if (v == type_[b * S_]) ltlog[b] = logf(l0 + 1e-16f) * mask_[b * S_];
  }
}

// ---------------- fused euler, 2-wave split:
//  wave0: msg/jump + f-chain (drift) + noise(t=0) + h update + hTl publish + h store
//  wave1: g-chain (diff) + e-chain/efin + noise(t=1) + trapezoid/acc + outputs
__launch_bounds__(128, 1)
__global__ void euler_k(const float* __restrict__ time_, const int* __restrict__ type_,
                        const float* __restrict__ mask_, const float* __restrict__ wsf,
                        const float* __restrict__ fb1, const float* __restrict__ fb2,
                        const float* __restrict__ fb3, const float* __restrict__ gb1,
                        const float* __restrict__ gb2, const float* __restrict__ gb3,
                        const float* __restrict__ eb1, const float* __restrict__ eb2,
                        const float* __restrict__ eW2, const float* __restrict__ fW1,
                        const float* __restrict__ gW1,
                        const float* __restrict__ mb1, const float* __restrict__ mb2,
                        const float* __restrict__ jb1, const float* __restrict__ jb2,
                        const float* __restrict__ hsrc, float* __restrict__ hdst,
                        float* __restrict__ acc, float* __restrict__ prevl,
                        float* __restrict__ prevt, float* __restrict__ ltlog,
                        float* __restrict__ dout, int s, SubK skc) {
  __shared__ unsigned short actF[16 * 72];
  __shared__ unsigned short actG[16 * 72];
  __shared__ unsigned short hTl[16 * 40];
  __shared__ float4 dtA[64];        // raw diff (t=0 cols)
  __shared__ float4 dtB[64];        // diff*sq*nz (t=1 cols)

  const int wv = threadIdx.x >> 6;          // 0 or 1
  const bool w1 = (wv == 1);
  const int lane = threadIdx.x & 63;
  const int g = lane >> 4, li = lane & 15;
  const int bid = blockIdx.x;
  const int b = bid / NTILE, tile = bid - b * NTILE;
  const int row0 = b * V_ + tile * 16;
  const int rmax = b * V_ + (V_ - 1);
  const int ev = type_[b * S_ + s - 1];

  const f16x8* WBv = (const f16x8*)wsf;
  const float* ep = wsf + WO_EP;

  // per-wave weight fragments in registers
  const int o1 = w1 ? 4 : 0, o2 = w1 ? 16 : 8, o3 = w1 ? 28 : 24;
  f16x8 wA[4], wB[8], wC[4], wE[4];
#pragma unroll
  for (int i = 0; i < 4; ++i) wA[i] = WBv[(o1 + i) * 64 + lane];
#pragma unroll
  for (int i = 0; i < 8; ++i) wB[i] = WBv[(o2 + i) * 64 + lane];
#pragma unroll
  for (int i = 0; i < 4; ++i) wC[i] = WBv[(o3 + i) * 64 + lane];
#pragma unroll
  for (int i = 0; i < 4; ++i) wE[i] = WBv[(32 + i) * 64 + lane];   // e1 (wave1 uses)

  // unified biases (wave-selected)
  float b1v[4], b2v[4], aw0[4], aw1[4], eb1v[4], e2v[4], mb1v[4], jb1v[4];
#pragma unroll
  for (int nt = 0; nt < 4; ++nt) {
    int n = li + 16 * nt;
    b1v[nt] = w1 ? gb1[n] : fb1[n];
    b2v[nt] = w1 ? gb2[n] : fb2[n];
    aw0[nt] = w1 ? gW1[32 * HID_ + n] : fW1[32 * HID_ + n];
    aw1[nt] = w1 ? 0.0f : fW1[33 * HID_ + n];
    eb1v[nt] = eb1[n]; e2v[nt] = eW2[n];
    mb1v[nt] = mb1[n]; jb1v[nt] = jb1[n];
  }
  float b3v[2], mb2v[2], jb2v[2];
#pragma unroll
  for (int nt = 0; nt < 2; ++nt) {
    b3v[nt] = w1 ? gb3[li + 16 * nt] : fb3[li + 16 * nt];
    mb2v[nt] = mb2[li + 16 * nt]; jb2v[nt] = jb2[li + 16 * nt];
  }
  const float eb2v = eb2[0];

  const float t0 = time_[b * S_ + s - 1], t1 = time_[b * S_ + s];
  const float dt = (t1 - t0) / 10.0f;
  const float sq = sqrtf(dt);
  const float msk = mask_[b * S_ + s], mskp = mask_[b * S_ + s - 1];

  float hv[2][4];

  // ================= wave0: h load + msg/jump (round-9 verified) =================
  if (!w1) {
#pragma unroll
    for (int t = 0; t < 2; ++t)
#pragma unroll
      for (int reg = 0; reg < 4; ++reg) {
        int rv = row0 + 4 * g + reg; if (rv > rmax) rv = rmax;
        hv[t][reg] = hsrc[rv * HD_ + li + 16 * t];
      }
    float sd0 = hsrc[(b * V_ + ev) * HD_ + li];
    float sd1 = hsrc[(b * V_ + ev) * HD_ + li + 16];
    uint32_t su = pk2(sd0, sd1);
#pragma unroll
    for (int reg = 0; reg < 4; ++reg) {
      *(uint32_t*)&actF[(4 * g + reg) * 72 + 2 * li] = su;
      *(uint32_t*)&actG[(4 * g + reg) * 72 + 2 * li] = pk2(hv[0][reg], hv[1][reg]);
    }
    LGKM_FENCE;
    f16x8 ap0 = *(const f16x8*)&actF[li * 72 + 8 * g];
    f16x8 ap1 = *(const f16x8*)&actG[li * 72 + 8 * g];
    f32x4 cm[4];
#pragma unroll
    for (int nt = 0; nt < 4; ++nt) {
      f32x4 c = {mb1v[nt], mb1v[nt], mb1v[nt], mb1v[nt]};
      c = MF(ap0, WBv[(38 + nt) * 64 + lane], c);
      cm[nt] = MF(ap1, WBv[(42 + nt) * 64 + lane], c);
    }
#pragma unroll
    for (int reg = 0; reg < 4; ++reg) {
      uint2 u;
      u.x = pk2(tanh_e(cm[0][reg]), tanh_e(cm[1][reg]));
      u.y = pk2(tanh_e(cm[2][reg]), tanh_e(cm[3][reg]));
      *(uint2*)&actF[(4 * g + reg) * 72 + 4 * li] = u;
    }
    LGKM_FENCE;
    f16x8 am0 = *(const f16x8*)&actF[li * 72 + 8 * g];
    f16x8 am1 = *(const f16x8*)&actF[li * 72 + 32 + 8 * g];
    f32x4 mm[2];
#pragma unroll
    for (int nt = 0; nt < 2; ++nt) {
      f32x4 c = {mb2v[nt], mb2v[nt], mb2v[nt], mb2v[nt]};
      c = MF(am0, WBv[(46 + nt) * 64 + lane], c);
      mm[nt] = MF(am1, WBv[(48 + nt) * 64 + lane], c);
    }
#pragma unroll
    for (int reg = 0; reg < 4; ++reg) {
      int v = tile * 16 + 4 * g + reg; int vc = (v < V_) ? v : (V_ - 1);
      float p = ep[ev * V_ + vc];
      hv[0][reg] += mm[0][reg] * p;
      hv[1][reg] += mm[1][reg] * p;
    }
    if (tile == (ev >> 4)) {
#pragma unroll
      for (int reg = 0; reg < 4; ++reg)
        *(uint32_t*)&hTl[(4 * g + reg) * 40 + 2 * li] = pk2(hv[0][reg], hv[1][reg]);
      LGKM_FENCE;
      f16x8 ah = *(const f16x8*)&hTl[li * 40 + 8 * g];
      f32x4 cj[4];
#pragma unroll
      for (int nt = 0; nt < 4; ++nt) {
        f32x4 c = {jb1v[nt], jb1v[nt], jb1v[nt], jb1v[nt]};
        cj[nt] = MF(ah, WBv[(50 + nt) * 64 + lane], c);
      }
#pragma unroll
      for (int reg = 0; reg < 4; ++reg) {
        uint2 u;
        u.x = pk2(tanh_e(cj[0][reg]), tanh_e(cj[1][reg]));
        u.y = pk2(tanh_e(cj[2][reg]), tanh_e(cj[3][reg]));
        *(uint2*)&actG[(4 * g + reg) * 72 + 4 * li] = u;
      }
      LGKM_FENCE;
      f16x8 aj0 = *(const f16x8*)&actG[li * 72 + 8 * g];
      f16x8 aj1 = *(const f16x8*)&actG[li * 72 + 32 + 8 * g];
      f32x4 jm[2];
#pragma unroll
      for (int nt = 0; nt < 2; ++nt) {
        f32x4 c = {jb2v[nt], jb2v[nt], jb2v[nt], jb2v[nt]};
        c = MF(aj0, WBv[(54 + nt) * 64 + lane], c);
        jm[nt] = MF(aj1, WBv[(56 + nt) * 64 + lane], c);
      }
#pragma unroll
      for (int reg = 0; reg < 4; ++reg)
        if (tile * 16 + 4 * g + reg == ev) {
          hv[0][reg] += jm[0][reg];
          hv[1][reg] += jm[1][reg];
        }
    }
#pragma unroll
    for (int reg = 0; reg < 4; ++reg)
      *(uint32_t*)&hTl[(4 * g + reg) * 40 + 2 * li] = pk2(hv[0][reg], hv[1][reg]);
  }

  // ================= wave1: accumulator state =================
  float accv[4] = {0.f, 0.f, 0.f, 0.f}, lprev[4], plv[4] = {0.f, 0.f, 0.f, 0.f};
  float ptv = 0.0f;
  if (w1) {
#pragma unroll
    for (int reg = 0; reg < 4; ++reg) {
      int rv = row0 + 4 * g + reg; if (rv > rmax) rv = rmax;
      accv[reg] = acc[rv];
      plv[reg] = (s > 1) ? prevl[rv] : 0.0f;
    }
    ptv = (s > 1) ? prevt[row0] : 0.0f;
  }

  auto efin = [&](f32x4* ce, float* lout) {
#pragma unroll
    for (int reg = 0; reg < 4; ++reg) {
      float p = tanh_e(ce[0][reg]) * e2v[0];
      p = fmaf(tanh_e(ce[1][reg]), e2v[1], p);
      p = fmaf(tanh_e(ce[2][reg]), e2v[2], p);
      p = fmaf(tanh_e(ce[3][reg]), e2v[3], p);
#pragma unroll
      for (int m = 1; m < 16; m <<= 1) p += __shfl_xor(p, m, 64);
      lout[reg] = softplus_fast(p + eb2v);
    }
  };

  __syncthreads();   // post-msg h published

  unsigned short* act = w1 ? actG : actF;

  // ================= main loop =================
#pragma unroll 1
  for (int j = 0; j < ND_; ++j) {
    float nzh[4];
    noise4(row0, lane, wv, skc.k[j][0], skc.k[j][1], nzh);  // wave0: t=0, wave1: t=1

    f16x8 ah = *(const f16x8*)&hTl[li * 40 + 8 * g];
    // e1 (wave1 only) shares A-frag
    f32x4 ce[4];
    if (w1) {
#pragma unroll
      for (int nt = 0; nt < 4; ++nt) {
        f32x4 c = {eb1v[nt], eb1v[nt], eb1v[nt], eb1v[nt]};
        ce[nt] = MF(ah, wE[nt], c);
      }
    }
    // L1
    f32x4 c1[4];
#pragma unroll
    for (int nt = 0; nt < 4; ++nt) {
      f32x4 c = {b1v[nt], b1v[nt], b1v[nt], b1v[nt]};
      c1[nt] = MF(ah, wA[nt], c);
    }
    const float dft = dt * (float)(j + 1);
    float addv[4];
#pragma unroll
    for (int nt = 0; nt < 4; ++nt) addv[nt] = dft * aw0[nt] + t0 * aw1[nt];
#pragma unroll
    for (int reg = 0; reg < 4; ++reg) {
      uint2 u;
      u.x = pk2(tanh_e(c1[0][reg] + addv[0]), tanh_e(c1[1][reg] + addv[1]));
      u.y = pk2(tanh_e(c1[2][reg] + addv[2]), tanh_e(c1[3][reg] + addv[3]));
      *(uint2*)&act[(4 * g + reg) * 72 + 4 * li] = u;
    }
    // wave1: finish e + trapezoid while LDS settles
    if (w1) {
      float lc[4];
      efin(ce, lc);
      if (j == 0) {
        if (s > 1) {
#pragma unroll
          for (int reg = 0; reg < 4; ++reg)
            accv[reg] += (plv[reg] * mskp + lc[reg] * msk) * (t0 - ptv) * msk;
        }
      } else {
        float dtm = dt * msk;
#pragma unroll
        for (int reg = 0; reg < 4; ++reg)
          accv[reg] += (lprev[reg] * msk + lc[reg] * msk) * dtm;
      }
#pragma unroll
      for (int reg = 0; reg < 4; ++reg) lprev[reg] = lc[reg];
    }
    LGKM_FENCE;
    // L2
    f16x8 a0 = *(const f16x8*)&act[li * 72 + 8 * g];
    f16x8 a1 = *(const f16x8*)&act[li * 72 + 32 + 8 * g];
    f32x4 c2[4];
#pragma unroll
    for (int nt = 0; nt < 4; ++nt) {
      f32x4 c = {b2v[nt], b2v[nt], b2v[nt], b2v[nt]};
      c = MF(a0, wB[2 * nt], c);
      c2[nt] = MF(a1, wB[2 * nt + 1], c);
    }
#pragma unroll
    for (int reg = 0; reg < 4; ++reg) {
      uint2 u;
      u.x = pk2(tanh_e(c2[0][reg]), tanh_e(c2[1][reg]));
      u.y = pk2(tanh_e(c2[2][reg]), tanh_e(c2[3][reg]));
      *(uint2*)&act[(4 * g + reg) * 72 + 4 * li] = u;
    }
    LGKM_FENCE;
    // L3
    a0 = *(const f16x8*)&act[li * 72 + 8 * g];
    a1 = *(const f16x8*)&act[li * 72 + 32 + 8 * g];
    f32x4 o3[2];
#pragma unroll
    for (int nt = 0; nt < 2; ++nt) {
      f32x4 c = {b3v[nt], b3v[nt], b3v[nt], b3v[nt]};
      c = MF(a0, wC[2 * nt], c);
      o3[nt] = MF(a1, wC[2 * nt + 1], c);
    }
    if (w1) {   // publish diff: raw t=0 half, premultiplied t=1 half
      float4 da; da.x = o3[0][0]; da.y = o3[0][1]; da.z = o3[0][2]; da.w = o3[0][3];
      float4 db; db.x = o3[1][0] * sq * nzh[0]; db.y = o3[1][1] * sq * nzh[1];
      db.z = o3[1][2] * sq * nzh[2]; db.w = o3[1][3] * sq * nzh[3];
      dtA[lane] = da; dtB[lane] = db;
    }
    __syncthreads();
    if (!w1) {  // h update + publish
      float4 da = dtA[lane], db = dtB[lane];
      hv[0][0] += o3[0][0] * dt + da.x * sq * nzh[0];
      hv[0][1] += o3[0][1] * dt + da.y * sq * nzh[1];
      hv[0][2] += o3[0][2] * dt + da.z * sq * nzh[2];
      hv[0][3] += o3[0][3] * dt + da.w * sq * nzh[3];
      hv[1][0] += o3[1][0] * dt + db.x;
      hv[1][1] += o3[1][1] * dt + db.y;
      hv[1][2] += o3[1][2] * dt + db.z;
      hv[1][3] += o3[1][3] * dt + db.w;
#pragma unroll
      for (int reg = 0; reg < 4; ++reg)
        *(uint32_t*)&hTl[(4 * g + reg) * 40 + 2 * li] = pk2(hv[0][reg], hv[1][reg]);
    }
    __syncthreads();
  }

  // ================= epilogue =================
  if (w1) {
    float llast[4];
    f16x8 ah = *(const f16x8*)&hTl[li * 40 + 8 * g];
    f32x4 ce[4];
#pragma unroll
    for (int nt = 0; nt < 4; ++nt) {
      f32x4 c = {eb1v[nt], eb1v[nt], eb1v[nt], eb1v[nt]};
      ce[nt] = MF(ah, wE[nt], c);
    }
    efin(ce, llast);
    float dtm = dt * msk;
#pragma unroll
    for (int reg = 0; reg < 4; ++reg)
      accv[reg] += (lprev[reg] * msk + llast[reg] * msk) * dtm;
    if (li == 0) {
      int evn = type_[b * S_ + s];
      float pt = t0 + dt * 10.0f;
#pragma unroll
      for (int reg = 0; reg < 4; ++reg) {
        int v = tile * 16 + 4 * g + reg;
        if (v < V_) {
          int rv = row0 + 4 * g + reg;
          acc[rv] = accv[reg];
          prevl[rv] = llast[reg];
          prevt[rv] = pt;
          dout[1 + (b * S_ + s) * V_ + v] = llast[reg];
          if (v == evn) ltlog[s * B_ + b] = logf(llast[reg] + 1e-16f) * msk;
        }
      }
    }
  } else {
#pragma unroll
    for (int t = 0; t < 2; ++t)
#pragma unroll
      for (int reg = 0; reg < 4; ++reg) {
        int v = tile * 16 + 4 * g + reg;
        if (v < V_) hdst[(row0 + 4 * g + reg) * HD_ + li + 16 * t] = hv[t][reg];
      }
  }
}

// ---------------- deterministic final reduce ----------------
__global__ void reduce_k(const float* __restrict__ acc, const float* __restrict__ ltlog,
                         float* __restrict__ dout) {
  __shared__ double sh[512];
  int t = threadIdx.x;
  double ia = 0.0, st = 0.0;
  for (int i = t; i < NROW; i += 256) ia += (double)acc[i];
  for (int i = t; i < B_ * S_; i += 256) st += (double)ltlog[i];
  sh[t] = ia; sh[256 + t] = st;
  __syncthreads();
  for (int o = 128; o > 0; o >>= 1) {
    if (t < o) { sh[t] += sh[t + o]; sh[256 + t] += sh[256 + t + o]; }
    __syncthreads();
  }
  if (t == 0) dout[0] = (float)(0.5 * sh[0] - sh[256]);
}

extern "C" void kernel_launch(void* const* d_in, const int* in_sizes, int n_in,
                              void* d_out, int out_size, void* d_ws, size_t ws_size,
                              hipStream_t stream) {
  const float* time_  = (const float*)d_in[0];
  const int*   type_  = (const int*)d_in[1];
  const float* mask_  = (const float*)d_in[2];
  const float* logits = (const float*)d_in[3];
  const float* h0     = (const float*)d_in[4];
  const float* fW1 = (const float*)d_in[5];  const float* fb1 = (const float*)d_in[6];
  const float* fW2 = (const float*)d_in[7];  const float* fb2 = (const float*)d_in[8];
  const float* fW3 = (const float*)d_in[9];  const float* fb3 = (const float*)d_in[10];
  const float* gW1 = (const float*)d_in[11]; const float* gb1 = (const float*)d_in[12];
  const float* gW2 = (const float*)d_in[13]; const float* gb2 = (const float*)d_in[14];
  const float* gW3 = (const float*)d_in[15]; const float* gb3 = (const float*)d_in[16];
  const float* eW1 = (const float*)d_in[17]; const float* eb1 = (const float*)d_in[18];
  const float* eW2 = (const float*)d_in[19]; const float* eb2 = (const float*)d_in[20];
  const float* jW1 = (const float*)d_in[21]; const float* jb1 = (const float*)d_in[22];
  const float* jW2 = (const float*)d_in[23]; const float* jb2 = (const float*)d_in[24];
  const float* mW1 = (const float*)d_in[25]; const float* mb1 = (const float*)d_in[26];
  const float* mW2 = (const float*)d_in[27]; const float* mb2 = (const float*)d_in[28];
  float* out = (float*)d_out;

  float* ws    = (float*)d_ws;
  float* hA    = ws + WO_HA;
  float* hB    = ws + WO_HB;
  float* acc   = ws + WO_ACC;
  float* prevl = ws + WO_PREVL;
  float* prevt = ws + WO_PREVT;
  float* ltlog = ws + WO_LTLOG;

  // host-side key chain: key(42); 310x fold-like split (verified bit-exact)
  uint32_t kh = 0u, kl = 42u;
  uint32_t subs[310][2];
  for (int n = 0; n < 310; ++n) {
    uint32_t a0 = 0u, a1 = 0u; tf2x32(kh, kl, a0, a1);
    uint32_t b0 = 0u, b1 = 1u; tf2x32(kh, kl, b0, b1);
    subs[n][0] = b0; subs[n][1] = b1;
    kh = a0; kl = a1;
  }

  prep_k<<<54, 256, 0, stream>>>(fW1, gW1, fW2, gW2, fW3, gW3, eW1, eW2,
                                 mW1, mW2, jW1, jW2, logits, ws);
  init_k<<<NROW / 4, 256, 0, stream>>>(type_, mask_, h0, eW1, eb1, eW2, eb2,
                                       hA, acc, ltlog, out);

  for (int s = 1; s <= 31; ++s) {
    const float* hs = (s & 1) ? hA : hB;
    float*       hd = (s & 1) ? hB : hA;
    SubK skc;
    for (int j = 0; j < ND_; ++j) {
      skc.k[j][0] = subs[(s - 1) * ND_ + j][0];
      skc.k[j][1] = subs[(s - 1) * ND_ + j][1];
    }
    euler_k<<<NBLK, 128, 0, stream>>>(time_, type_, mask_, ws,
                                      fb1, fb2, fb3, gb1, gb2, gb3, eb1, eb2, eW2,
                                      fW1, gW1, mb1, mb2, jb1, jb2,
                                      hs, hd, acc, prevl, prevt, ltlog, out,
                                      s, skc);
  }
  reduce_k<<<1, 256, 0, stream>>>(acc, ltlog, out);
}